// Round 4
// baseline (306.385 us; speedup 1.0000x reference)
//
#include <hip/hip_runtime.h>

// ---------------------------------------------------------------------------
// CrossAttention (BLT-style patch cross-attention), MI355X gfx950
// B=2, S=4096, P=1024, D=1024, H=16, dh=64
//
// Round 4:
//   - attention: S^T formulation. Wave owns a 16-col c-range; P^T exits the
//     QK^T MFMA in exactly the B-frag layout of 16x16x16 MFMA -> PV straight
//     from registers (no P LDS round-trip; each wave reads only its K/V share)
//   - fused convert kernel (1 launch), fused K+V projection (1 launch)
// ---------------------------------------------------------------------------

#define B_ 2
#define S_ 4096
#define P_ 1024
#define D_ 1024
#define H_ 16
#define DH_ 64

typedef __attribute__((ext_vector_type(8))) short short8;
typedef __attribute__((ext_vector_type(4))) short s16x4;
typedef __attribute__((ext_vector_type(4))) float f32x4;

#define KSCALE 0.18033688011112042f  /* 1/sqrt(64) * log2(e) */

#if __has_builtin(__builtin_amdgcn_mfma_f32_16x16x16bf16_1k)
#define MFMA16(a, b, c) __builtin_amdgcn_mfma_f32_16x16x16bf16_1k(a, b, c, 0, 0, 0)
#elif __has_builtin(__builtin_amdgcn_mfma_f32_16x16x16_bf16)
#define MFMA16(a, b, c) __builtin_amdgcn_mfma_f32_16x16x16_bf16(a, b, c, 0, 0, 0)
#else
static __device__ __forceinline__ f32x4 mfma16_asm(s16x4 a, s16x4 b, f32x4 c) {
    asm volatile("v_mfma_f32_16x16x16_bf16 %0, %1, %2, %0"
                 : "+v"(c) : "v"(a), "v"(b));
    return c;
}
#define MFMA16(a, b, c) mfma16_asm(a, b, c)
#endif

static __device__ __forceinline__ unsigned short f2bf(float f) {
    unsigned int u = __float_as_uint(f);
    u += 0x7FFFu + ((u >> 16) & 1u);   // round-to-nearest-even
    return (unsigned short)(u >> 16);
}

// async 16B global -> LDS (wave-uniform lds base + lane*16)
static __device__ __forceinline__ void gll16(const unsigned short* g,
                                             const unsigned short* l) {
    __builtin_amdgcn_global_load_lds(
        (const __attribute__((address_space(1))) unsigned int*)g,
        (__attribute__((address_space(3))) unsigned int*)l,
        16, 0, 0);
}

// ---------------------------------------------------------------------------
// fused fp32 -> bf16 conversion of all six tensors (single launch)
// segment sizes in float4 units; all multiples of 256
// ---------------------------------------------------------------------------
__global__ __launch_bounds__(256) void xattn_convert_all(
    const float* __restrict__ queries, const float* __restrict__ patches,
    const float* __restrict__ wq, const float* __restrict__ wk,
    const float* __restrict__ wv, const float* __restrict__ wo,
    unsigned short* __restrict__ qb, unsigned short* __restrict__ pb,
    unsigned short* __restrict__ wqb, unsigned short* __restrict__ wkb,
    unsigned short* __restrict__ wvb, unsigned short* __restrict__ wob) {
    const int NQ = (B_ * S_ * D_) / 4;      // 2097152
    const int NP = (B_ * P_ * D_) / 4;      // 524288
    const int NW = (D_ * D_) / 4;           // 262144
    int i = blockIdx.x * 256 + threadIdx.x;
    const float* src;
    unsigned short* dst;
    int j;
    if (i < NQ) { src = queries; dst = qb; j = i; }
    else if (i < NQ + NP) { src = patches; dst = pb; j = i - NQ; }
    else {
        int k = i - NQ - NP;
        int wsel = k >> 18;                  // NW = 2^18
        j = k & (NW - 1);
        if (wsel == 0) { src = wq; dst = wqb; }
        else if (wsel == 1) { src = wk; dst = wkb; }
        else if (wsel == 2) { src = wv; dst = wvb; }
        else { src = wo; dst = wob; }
    }
    float4 v = ((const float4*)src)[j];
    ushort4 o;
    o.x = f2bf(v.x); o.y = f2bf(v.y); o.z = f2bf(v.z); o.w = f2bf(v.w);
    ((ushort4*)dst)[j] = o;
}

// ---------------------------------------------------------------------------
// inclusive cumsum of patch_boundaries per batch row
// ---------------------------------------------------------------------------
__global__ __launch_bounds__(1024) void xattn_cumsum(
    const int* __restrict__ bounds, int* __restrict__ pidx) {
    __shared__ int sdata[1024];
    int b = blockIdx.x;
    int t = threadIdx.x;
    const int* src = bounds + b * S_ + t * 4;
    int b0 = src[0], b1 = src[1], b2 = src[2], b3 = src[3];
    int s0 = b0, s1 = s0 + b1, s2 = s1 + b2, s3 = s2 + b3;
    sdata[t] = s3;
    __syncthreads();
    for (int off = 1; off < 1024; off <<= 1) {
        int v = 0;
        if (t >= off) v = sdata[t - off];
        __syncthreads();
        sdata[t] += v;
        __syncthreads();
    }
    int prefix = (t > 0) ? sdata[t - 1] : 0;
    int* dst = pidx + b * S_ + t * 4;
    dst[0] = prefix + s0;
    dst[1] = prefix + s1;
    dst[2] = prefix + s2;
    dst[3] = prefix + s3;
}

// ---------------------------------------------------------------------------
// fused K+V projection: 64x64 tile, blockIdx.z selects K (bf16 [M,N]) or
// V (bf16 transposed per-head [b][h][dh][P]).
// ---------------------------------------------------------------------------
__global__ __launch_bounds__(256) void xattn_gemm_kv(
    const unsigned short* __restrict__ A,
    const unsigned short* __restrict__ Wk,
    const unsigned short* __restrict__ Wv,
    const float* __restrict__ bk, const float* __restrict__ bv,
    unsigned short* __restrict__ Kout, unsigned short* __restrict__ Vout) {
    const int K = 1024, N = 1024;
    __shared__ unsigned short As[64 * 32];
    __shared__ unsigned short Bs[64 * 32];

    const int isV = blockIdx.z;
    const unsigned short* W = isV ? Wv : Wk;
    const float* bias = isV ? bv : bk;

    int m0 = blockIdx.y * 64;
    int n0 = blockIdx.x * 64;
    int t = threadIdx.x;
    int w = t >> 6;
    int l = t & 63;
    int lrow = t >> 2;
    int lcg = t & 3;

    f32x4 acc0 = {0.f, 0.f, 0.f, 0.f};
    f32x4 acc1 = {0.f, 0.f, 0.f, 0.f};
    f32x4 acc2 = {0.f, 0.f, 0.f, 0.f};
    f32x4 acc3 = {0.f, 0.f, 0.f, 0.f};

    const unsigned short* Aptr = A + (size_t)(m0 + lrow) * K + lcg * 8;
    const unsigned short* Wptr = W + (size_t)(n0 + lrow) * K + lcg * 8;

    int fr = l & 15;
    int fq = l >> 4;
    const unsigned short* a_lds = &As[(w * 16 + fr) * 32 + fq * 8];
    const unsigned short* b0_lds = &Bs[(0 * 16 + fr) * 32 + fq * 8];
    const unsigned short* b1_lds = &Bs[(1 * 16 + fr) * 32 + fq * 8];
    const unsigned short* b2_lds = &Bs[(2 * 16 + fr) * 32 + fq * 8];
    const unsigned short* b3_lds = &Bs[(3 * 16 + fr) * 32 + fq * 8];
    unsigned short* a_st = &As[lrow * 32 + lcg * 8];
    unsigned short* b_st = &Bs[lrow * 32 + lcg * 8];

    for (int k0 = 0; k0 < K; k0 += 32) {
        *(float4*)a_st = *(const float4*)(Aptr + k0);
        *(float4*)b_st = *(const float4*)(Wptr + k0);
        __syncthreads();
        short8 af = *(const short8*)a_lds;
        short8 bf0 = *(const short8*)b0_lds;
        short8 bf1 = *(const short8*)b1_lds;
        short8 bf2 = *(const short8*)b2_lds;
        short8 bf3 = *(const short8*)b3_lds;
        acc0 = __builtin_amdgcn_mfma_f32_16x16x32_bf16(af, bf0, acc0, 0, 0, 0);
        acc1 = __builtin_amdgcn_mfma_f32_16x16x32_bf16(af, bf1, acc1, 0, 0, 0);
        acc2 = __builtin_amdgcn_mfma_f32_16x16x32_bf16(af, bf2, acc2, 0, 0, 0);
        acc3 = __builtin_amdgcn_mfma_f32_16x16x32_bf16(af, bf3, acc3, 0, 0, 0);
        __syncthreads();
    }

    int r0 = fq * 4;
    f32x4 accs[4] = {acc0, acc1, acc2, acc3};
#pragma unroll
    for (int j = 0; j < 4; ++j) {
        int n = n0 + j * 16 + fr;
        float bvv = bias[n];
#pragma unroll
        for (int r = 0; r < 4; ++r) {
            int m = m0 + w * 16 + r0 + r;
            float val = accs[j][r] + bvv;
            if (!isV) {
                Kout[(size_t)m * N + n] = f2bf(val);
            } else {
                int bb = m >> 10, c = m & (P_ - 1);
                int hh = n >> 6, d = n & 63;
                Vout[(((size_t)(bb * H_ + hh)) * 64 + d) * P_ + c] = f2bf(val);
            }
        }
    }
}

// ---------------------------------------------------------------------------
// 128x128-tile GEMM, global_load_lds staging (m97 recipe), BK=32, 4 waves.
// MODE 0: fp32 out.  MODE 3: bf16 out scaled by KSCALE (Q projection).
// ---------------------------------------------------------------------------
template <int MODE>
__global__ __launch_bounds__(256) void xattn_gemm128(
    const unsigned short* __restrict__ A,
    const unsigned short* __restrict__ W,
    const float* __restrict__ bias,
    void* __restrict__ Cout, int M) {
    const int K = 1024, N = 1024;
    __shared__ unsigned short As[128 * 32];
    __shared__ unsigned short Bs[128 * 32];

    const int m0 = blockIdx.y * 128;
    const int n0 = blockIdx.x * 128;
    const int t = threadIdx.x;
    const int w = t >> 6;
    const int l = t & 63;
    const int fr = l & 15, fq = l >> 4;
    const int wr = w >> 1, wc = w & 1;

    const int r0s = t >> 2;
    const int cs = (t & 3) * 8;
    const unsigned short* Ap0 = A + (size_t)(m0 + r0s) * K + cs;
    const unsigned short* Ap1 = A + (size_t)(m0 + 64 + r0s) * K + cs;
    const unsigned short* Wp0 = W + (size_t)(n0 + r0s) * K + cs;
    const unsigned short* Wp1 = W + (size_t)(n0 + 64 + r0s) * K + cs;
    const unsigned short* lA0 = &As[(w * 64) * 8];
    const unsigned short* lA1 = &As[(256 + w * 64) * 8];
    const unsigned short* lB0 = &Bs[(w * 64) * 8];
    const unsigned short* lB1 = &Bs[(256 + w * 64) * 8];

    f32x4 acc[4][4];
#pragma unroll
    for (int i = 0; i < 4; ++i)
#pragma unroll
        for (int j = 0; j < 4; ++j) acc[i][j] = (f32x4){0.f, 0.f, 0.f, 0.f};

    for (int k0 = 0; k0 < K; k0 += 32) {
        gll16(Ap0 + k0, lA0);
        gll16(Ap1 + k0, lA1);
        gll16(Wp0 + k0, lB0);
        gll16(Wp1 + k0, lB1);
        __syncthreads();
        short8 af[4], bf[4];
#pragma unroll
        for (int i = 0; i < 4; ++i)
            af[i] = *(const short8*)&As[(wr * 64 + i * 16 + fr) * 32 + fq * 8];
#pragma unroll
        for (int j = 0; j < 4; ++j)
            bf[j] = *(const short8*)&Bs[(wc * 64 + j * 16 + fr) * 32 + fq * 8];
#pragma unroll
        for (int i = 0; i < 4; ++i)
#pragma unroll
            for (int j = 0; j < 4; ++j)
                acc[i][j] = __builtin_amdgcn_mfma_f32_16x16x32_bf16(af[i], bf[j], acc[i][j], 0, 0, 0);
        __syncthreads();
    }

#pragma unroll
    for (int j = 0; j < 4; ++j) {
        int n = n0 + wc * 64 + j * 16 + fr;
        float bv = bias[n];
#pragma unroll
        for (int i = 0; i < 4; ++i) {
            int mbase = m0 + wr * 64 + i * 16 + fq * 4;
#pragma unroll
            for (int r = 0; r < 4; ++r) {
                float val = acc[i][j][r] + bv;
                if (MODE == 0) {
                    ((float*)Cout)[(size_t)(mbase + r) * N + n] = val;
                } else {
                    ((unsigned short*)Cout)[(size_t)(mbase + r) * N + n] = f2bf(val * KSCALE);
                }
            }
        }
    }
}

// ---------------------------------------------------------------------------
// MFMA flash attention, S^T formulation.
// Block = 4 waves, 64 q-rows x 64 patch-cols per tile; wave w owns
// c-range [w*16, w*16+16).
//   S^T[c][q] via 16x16x32 (A=K rows from LDS, B=Q rows in regs).
//   exp2 (shift-invariant; Q pre-scaled), perm-pack -> P^T B-frags in regs.
//   O^T[d][q] partial via 16x16x16 (A=V^T rows from LDS, B=P^T regs).
// Cross-wave O^T/l reduction once at epilogue via LDS (union with K/V tiles).
// ---------------------------------------------------------------------------
__global__ __launch_bounds__(256) void xattn_attn_mfma(
    const unsigned short* __restrict__ Qb,   // [B*S][D] bf16 (pre-scaled)
    const unsigned short* __restrict__ Kb,   // [B*P][D] bf16
    const unsigned short* __restrict__ Vtb,  // [B][H][64][P] bf16
    const int* __restrict__ pidx,
    unsigned short* __restrict__ Ob) {       // [B*S][D] bf16
    __shared__ union SM {
        struct { unsigned short Ks[64 * 72]; unsigned short Vs[64 * 72]; } kv;
        float Obuf[64 * 65];
    } sm;
    __shared__ float lbuf[256];

    const int q0 = (63 - blockIdx.x) * 64;   // LPT: heavy blocks dispatch first
    const int h = blockIdx.y;
    const int b = blockIdx.z;
    const int t = threadIdx.x;
    const int w = t >> 6, l = t & 63;
    const int fr = l & 15, fq = l >> 4;

    // Q B-frags: qf[iq][half], lane: q = 16*iq + fr, k = fq*8+j (+32*half)
    short8 qf[4][2];
    {
        const unsigned short* qbase =
            Qb + (size_t)(b * S_ + q0 + fr) * D_ + h * DH_ + fq * 8;
#pragma unroll
        for (int iq = 0; iq < 4; ++iq) {
            qf[iq][0] = *(const short8*)(qbase + (size_t)(16 * iq) * D_);
            qf[iq][1] = *(const short8*)(qbase + (size_t)(16 * iq) * D_ + 32);
        }
    }
    int prow[4];
#pragma unroll
    for (int iq = 0; iq < 4; ++iq)
        prow[iq] = pidx[b * S_ + q0 + 16 * iq + fr];
    const int limit = pidx[b * S_ + q0 + 63];       // monotone in s
    const int ntiles = (min(limit, P_ - 1) + 64) >> 6;
    const int nfull = (pidx[b * S_ + q0] + 1) >> 6; // tiles needing no mask

    float lsum[4] = {0.f, 0.f, 0.f, 0.f};
    f32x4 oacc[4][4];   // [id][iq]: O^T partial, d=16id+fq*4+r, q=16iq+fr
#pragma unroll
    for (int id = 0; id < 4; ++id)
#pragma unroll
        for (int iq = 0; iq < 4; ++iq) oacc[id][iq] = (f32x4){0.f, 0.f, 0.f, 0.f};

    const int srow = t >> 3, sseg = t & 7;
    const unsigned short* kbase = Kb + (size_t)(b * P_) * D_ + h * DH_;
    const unsigned short* vbase = Vtb + (size_t)(b * H_ + h) * 64 * P_;

    for (int kt = 0; kt < ntiles; ++kt) {
        const int c0 = kt * 64;
        __syncthreads();   // protect LDS from previous tile's readers
        *(uint4*)&sm.kv.Ks[srow * 72 + sseg * 8] =
            *(const uint4*)(kbase + (size_t)(c0 + srow) * D_ + sseg * 8);
        *(uint4*)&sm.kv.Ks[(srow + 32) * 72 + sseg * 8] =
            *(const uint4*)(kbase + (size_t)(c0 + srow + 32) * D_ + sseg * 8);
        *(uint4*)&sm.kv.Vs[srow * 72 + sseg * 8] =
            *(const uint4*)(vbase + (size_t)srow * P_ + c0 + sseg * 8);
        *(uint4*)&sm.kv.Vs[(srow + 32) * 72 + sseg * 8] =
            *(const uint4*)(vbase + (size_t)(srow + 32) * P_ + c0 + sseg * 8);
        __syncthreads();

        // S^T: m = c (wave's 16 cols), n = q (4 quarters), K = dh = 64
        short8 ka0 = *(const short8*)&sm.kv.Ks[(w * 16 + fr) * 72 + fq * 8];
        short8 ka1 = *(const short8*)&sm.kv.Ks[(w * 16 + fr) * 72 + 32 + fq * 8];
        f32x4 st[4];
#pragma unroll
        for (int iq = 0; iq < 4; ++iq) {
            f32x4 a = (f32x4){0.f, 0.f, 0.f, 0.f};
            a = __builtin_amdgcn_mfma_f32_16x16x32_bf16(ka0, qf[iq][0], a, 0, 0, 0);
            a = __builtin_amdgcn_mfma_f32_16x16x32_bf16(ka1, qf[iq][1], a, 0, 0, 0);
            st[iq] = a;   // lane: q = 16iq+fr, c = c0 + w*16 + fq*4 + r
        }

        // exp2 + (boundary-only) mask + lsum; pack P^T into B-frags (truncate)
        s16x4 pfrag[4];
        const int cbase = c0 + w * 16 + fq * 4;
        if (kt >= nfull) {
#pragma unroll
            for (int iq = 0; iq < 4; ++iq) {
                float p0 = exp2f(st[iq][0]); p0 = (cbase + 0 > prow[iq]) ? 0.f : p0;
                float p1 = exp2f(st[iq][1]); p1 = (cbase + 1 > prow[iq]) ? 0.f : p1;
                float p2 = exp2f(st[iq][2]); p2 = (cbase + 2 > prow[iq]) ? 0.f : p2;
                float p3 = exp2f(st[iq][3]); p3 = (cbase + 3 > prow[iq]) ? 0.f : p3;
                lsum[iq] += (p0 + p1) + (p2 + p3);
                union { uint2 u; s16x4 s; } pu;
                pu.u.x = __builtin_amdgcn_perm(__float_as_uint(p1), __float_as_uint(p0), 0x07060302u);
                pu.u.y = __builtin_amdgcn_perm(__float_as_uint(p3), __float_as_uint(p2), 0x07060302u);
                pfrag[iq] = pu.s;
            }
        } else {
#pragma unroll
            for (int iq = 0; iq < 4; ++iq) {
                float p0 = exp2f(st[iq][0]);
                float p1 = exp2f(st[iq][1]);
                float p2 = exp2f(st[iq][2]);
                float p3 = exp2f(st[iq][3]);
                lsum[iq] += (p0 + p1) + (p2 + p3);
                union { uint2 u; s16x4 s; } pu;
                pu.u.x = __builtin_amdgcn_perm(__float_as_uint(p1), __float_as_uint(p0), 0x07060302u);
                pu.u.y = __builtin_amdgcn_perm(__float_as_uint(p3), __float_as_uint(p2), 0x07060302u);
                pfrag[iq] = pu.s;
            }
        }

        // PV: O^T[d][q] += V^T[d][c] * P^T[c][q], K = wave's 16 c's
#pragma unroll
        for (int id = 0; id < 4; ++id) {
            s16x4 va = *(const s16x4*)&sm.kv.Vs[(16 * id + fr) * 72 + w * 16 + fq * 4];
#pragma unroll
            for (int iq = 0; iq < 4; ++iq)
                oacc[id][iq] = MFMA16(va, pfrag[iq], oacc[id][iq]);
        }
    }

    // l: reduce over fq quads (c-slices within wave), publish per wave
#pragma unroll
    for (int iq = 0; iq < 4; ++iq) {
        lsum[iq] += __shfl_xor(lsum[iq], 16);
        lsum[iq] += __shfl_xor(lsum[iq], 32);
    }
    if (fq == 0) {
#pragma unroll
        for (int iq = 0; iq < 4; ++iq)
            lbuf[w * 64 + iq * 16 + fr] = lsum[iq];
    }
    __syncthreads();   // all waves done with kv tiles; Obuf may now alias them

    // O^T cross-wave reduction, serialized by wave
#pragma unroll
    for (int ph = 0; ph < 4; ++ph) {
        if (w == ph) {
#pragma unroll
            for (int id = 0; id < 4; ++id)
#pragma unroll
                for (int iq = 0; iq < 4; ++iq)
#pragma unroll
                    for (int r = 0; r < 4; ++r) {
                        int idx = (16 * id + 4 * fq + r) * 65 + 16 * iq + fr;
                        if (ph == 0) sm.Obuf[idx] = oacc[id][iq][r];
                        else sm.Obuf[idx] += oacc[id][iq][r];
                    }
        }
        __syncthreads();
    }

    // final: wave w handles d-range [16w,16w+16), lane l = q row
    float lv = lbuf[l] + lbuf[64 + l] + lbuf[128 + l] + lbuf[192 + l];
    float inv = 1.0f / lv;
    unsigned short o[16];
#pragma unroll
    for (int i = 0; i < 16; ++i)
        o[i] = f2bf(sm.Obuf[(16 * w + i) * 65 + l] * inv);
    uint4 u0, u1;
    u0.x = (unsigned)o[0] | ((unsigned)o[1] << 16);
    u0.y = (unsigned)o[2] | ((unsigned)o[3] << 16);
    u0.z = (unsigned)o[4] | ((unsigned)o[5] << 16);
    u0.w = (unsigned)o[6] | ((unsigned)o[7] << 16);
    u1.x = (unsigned)o[8] | ((unsigned)o[9] << 16);
    u1.y = (unsigned)o[10] | ((unsigned)o[11] << 16);
    u1.z = (unsigned)o[12] | ((unsigned)o[13] << 16);
    u1.w = (unsigned)o[14] | ((unsigned)o[15] << 16);
    unsigned short* orow = Ob + (size_t)(b * S_ + q0 + l) * D_ + h * DH_ + 16 * w;
    *(uint4*)orow = u0;
    *(uint4*)(orow + 8) = u1;
}

// ---------------------------------------------------------------------------
// launch
// ---------------------------------------------------------------------------
extern "C" void kernel_launch(void* const* d_in, const int* in_sizes, int n_in,
                              void* d_out, int out_size, void* d_ws, size_t ws_size,
                              hipStream_t stream) {
    const float* queries = (const float*)d_in[0];
    const float* patches = (const float*)d_in[1];
    const int* bounds    = (const int*)d_in[2];
    const float* wq = (const float*)d_in[3];
    const float* wk = (const float*)d_in[4];
    const float* wv = (const float*)d_in[5];
    const float* wo = (const float*)d_in[6];
    const float* bq = (const float*)d_in[7];
    const float* bk = (const float*)d_in[8];
    const float* bv = (const float*)d_in[9];
    const float* bo = (const float*)d_in[10];
    float* out = (float*)d_out;

    char* ws = (char*)d_ws;
    unsigned short* qb    = (unsigned short*)(ws + 0);          // 16777216
    unsigned short* pb    = (unsigned short*)(ws + 16777216);   // 4194304
    unsigned short* wqb   = (unsigned short*)(ws + 20971520);   // 2097152
    unsigned short* wkb   = (unsigned short*)(ws + 23068672);
    unsigned short* wvb   = (unsigned short*)(ws + 25165824);
    unsigned short* wob   = (unsigned short*)(ws + 27262976);
    unsigned short* Qbf   = (unsigned short*)(ws + 29360128);   // 16777216
    unsigned short* Kbf   = (unsigned short*)(ws + 46137344);   // 4194304
    unsigned short* Vtb   = (unsigned short*)(ws + 50331648);   // 4194304
    unsigned short* attnb = (unsigned short*)(ws + 54525952);   // 16777216
    int* pidx             = (int*)(ws + 71303168);              // 32768

    // 1. fused converts (total 3670016 float4s / 256 = 14336 blocks)
    xattn_convert_all<<<dim3(14336), 256, 0, stream>>>(
        queries, patches, wq, wk, wv, wo, qb, pb, wqb, wkb, wvb, wob);
    // 2. cumsum
    xattn_cumsum<<<dim3(B_), 1024, 0, stream>>>(bounds, pidx);
    // 3. projections
    xattn_gemm128<3><<<dim3(8, 64), 256, 0, stream>>>(qb, wqb, bq, (void*)Qbf, B_ * S_);
    xattn_gemm_kv<<<dim3(16, 32, 2), 256, 0, stream>>>(pb, wkb, wvb, bk, bv, Kbf, Vtb);
    // 4. MFMA flash attention (S^T formulation)
    xattn_attn_mfma<<<dim3(S_ / 64, H_, B_), 256, 0, stream>>>(Qbf, Kbf, Vtb, pidx, attnb);
    // 5. output projection (fp32 out)
    xattn_gemm128<0><<<dim3(8, 64), 256, 0, stream>>>(attnb, wob, bo, out, B_ * S_);
}

// Round 5
// 300.787 us; speedup vs baseline: 1.0186x; 1.0186x over previous
//
#include <hip/hip_runtime.h>

// ---------------------------------------------------------------------------
// CrossAttention (BLT-style patch cross-attention), MI355X gfx950
// B=2, S=4096, P=1024, D=1024, H=16, dh=64
//
// Round 5:
//   - attention: R3 orientation (MFMA32-only, b128 LDS reads), but 128 q-rows
//     per block (2 strips/wave) -> K/V LDS reads amortized over 2x compute.
//   - cumsum fused into the convert kernel (one fewer launch).
//   - keep: fused convert, fused K+V GEMM, 128-tile gll GEMMs for Q/O proj.
// ---------------------------------------------------------------------------

#define B_ 2
#define S_ 4096
#define P_ 1024
#define D_ 1024
#define H_ 16
#define DH_ 64

#define NCONV 14336   /* convert blocks: (2097152+524288+4*262144)/256 */

typedef __attribute__((ext_vector_type(8))) short short8;
typedef __attribute__((ext_vector_type(4))) float f32x4;

#define KSCALE 0.18033688011112042f  /* 1/sqrt(64) * log2(e) */

static __device__ __forceinline__ unsigned short f2bf(float f) {
    unsigned int u = __float_as_uint(f);
    u += 0x7FFFu + ((u >> 16) & 1u);   // round-to-nearest-even
    return (unsigned short)(u >> 16);
}

// async 16B global -> LDS (wave-uniform lds base + lane*16)
static __device__ __forceinline__ void gll16(const unsigned short* g,
                                             const unsigned short* l) {
    __builtin_amdgcn_global_load_lds(
        (const __attribute__((address_space(1))) unsigned int*)g,
        (__attribute__((address_space(3))) unsigned int*)l,
        16, 0, 0);
}

// ---------------------------------------------------------------------------
// fused fp32 -> bf16 conversion of all six tensors + cumsum (single launch)
// blocks [0, NCONV): convert; blocks NCONV+b: inclusive cumsum of batch b
// ---------------------------------------------------------------------------
__global__ __launch_bounds__(256) void xattn_convert_all(
    const float* __restrict__ queries, const float* __restrict__ patches,
    const float* __restrict__ wq, const float* __restrict__ wk,
    const float* __restrict__ wv, const float* __restrict__ wo,
    unsigned short* __restrict__ qb, unsigned short* __restrict__ pb,
    unsigned short* __restrict__ wqb, unsigned short* __restrict__ wkb,
    unsigned short* __restrict__ wvb, unsigned short* __restrict__ wob,
    const int* __restrict__ bounds, int* __restrict__ pidx) {
    if (blockIdx.x >= NCONV) {
        // ---- cumsum path: one block per batch, 256 threads x 16 elems ----
        __shared__ int sdata[256];
        int b = blockIdx.x - NCONV;
        int t = threadIdx.x;
        const int* src = bounds + b * S_ + t * 16;
        int vals[16];
        int run = 0;
#pragma unroll
        for (int i = 0; i < 16; ++i) { run += src[i]; vals[i] = run; }
        sdata[t] = run;
        __syncthreads();
        for (int off = 1; off < 256; off <<= 1) {
            int v = (t >= off) ? sdata[t - off] : 0;
            __syncthreads();
            sdata[t] += v;
            __syncthreads();
        }
        int prefix = (t > 0) ? sdata[t - 1] : 0;
        int* dst = pidx + b * S_ + t * 16;
#pragma unroll
        for (int i = 0; i < 16; ++i) dst[i] = prefix + vals[i];
        return;
    }
    // ---- convert path ----
    const int NQ = (B_ * S_ * D_) / 4;      // 2097152
    const int NP = (B_ * P_ * D_) / 4;      // 524288
    const int NW = (D_ * D_) / 4;           // 262144
    int i = blockIdx.x * 256 + threadIdx.x;
    const float* src;
    unsigned short* dst;
    int j;
    if (i < NQ) { src = queries; dst = qb; j = i; }
    else if (i < NQ + NP) { src = patches; dst = pb; j = i - NQ; }
    else {
        int k = i - NQ - NP;
        int wsel = k >> 18;                  // NW = 2^18
        j = k & (NW - 1);
        if (wsel == 0) { src = wq; dst = wqb; }
        else if (wsel == 1) { src = wk; dst = wkb; }
        else if (wsel == 2) { src = wv; dst = wvb; }
        else { src = wo; dst = wob; }
    }
    float4 v = ((const float4*)src)[j];
    ushort4 o;
    o.x = f2bf(v.x); o.y = f2bf(v.y); o.z = f2bf(v.z); o.w = f2bf(v.w);
    ((ushort4*)dst)[j] = o;
}

// ---------------------------------------------------------------------------
// fused K+V projection: 64x64 tile, blockIdx.z selects K (bf16 [M,N]) or
// V (bf16 transposed per-head [b][h][dh][P]).
// ---------------------------------------------------------------------------
__global__ __launch_bounds__(256) void xattn_gemm_kv(
    const unsigned short* __restrict__ A,
    const unsigned short* __restrict__ Wk,
    const unsigned short* __restrict__ Wv,
    const float* __restrict__ bk, const float* __restrict__ bv,
    unsigned short* __restrict__ Kout, unsigned short* __restrict__ Vout) {
    const int K = 1024, N = 1024;
    __shared__ unsigned short As[64 * 32];
    __shared__ unsigned short Bs[64 * 32];

    const int isV = blockIdx.z;
    const unsigned short* W = isV ? Wv : Wk;
    const float* bias = isV ? bv : bk;

    int m0 = blockIdx.y * 64;
    int n0 = blockIdx.x * 64;
    int t = threadIdx.x;
    int w = t >> 6;
    int l = t & 63;
    int lrow = t >> 2;
    int lcg = t & 3;

    f32x4 acc0 = {0.f, 0.f, 0.f, 0.f};
    f32x4 acc1 = {0.f, 0.f, 0.f, 0.f};
    f32x4 acc2 = {0.f, 0.f, 0.f, 0.f};
    f32x4 acc3 = {0.f, 0.f, 0.f, 0.f};

    const unsigned short* Aptr = A + (size_t)(m0 + lrow) * K + lcg * 8;
    const unsigned short* Wptr = W + (size_t)(n0 + lrow) * K + lcg * 8;

    int fr = l & 15;
    int fq = l >> 4;
    const unsigned short* a_lds = &As[(w * 16 + fr) * 32 + fq * 8];
    const unsigned short* b0_lds = &Bs[(0 * 16 + fr) * 32 + fq * 8];
    const unsigned short* b1_lds = &Bs[(1 * 16 + fr) * 32 + fq * 8];
    const unsigned short* b2_lds = &Bs[(2 * 16 + fr) * 32 + fq * 8];
    const unsigned short* b3_lds = &Bs[(3 * 16 + fr) * 32 + fq * 8];
    unsigned short* a_st = &As[lrow * 32 + lcg * 8];
    unsigned short* b_st = &Bs[lrow * 32 + lcg * 8];

    for (int k0 = 0; k0 < K; k0 += 32) {
        *(float4*)a_st = *(const float4*)(Aptr + k0);
        *(float4*)b_st = *(const float4*)(Wptr + k0);
        __syncthreads();
        short8 af = *(const short8*)a_lds;
        short8 bf0 = *(const short8*)b0_lds;
        short8 bf1 = *(const short8*)b1_lds;
        short8 bf2 = *(const short8*)b2_lds;
        short8 bf3 = *(const short8*)b3_lds;
        acc0 = __builtin_amdgcn_mfma_f32_16x16x32_bf16(af, bf0, acc0, 0, 0, 0);
        acc1 = __builtin_amdgcn_mfma_f32_16x16x32_bf16(af, bf1, acc1, 0, 0, 0);
        acc2 = __builtin_amdgcn_mfma_f32_16x16x32_bf16(af, bf2, acc2, 0, 0, 0);
        acc3 = __builtin_amdgcn_mfma_f32_16x16x32_bf16(af, bf3, acc3, 0, 0, 0);
        __syncthreads();
    }

    int r0 = fq * 4;
    f32x4 accs[4] = {acc0, acc1, acc2, acc3};
#pragma unroll
    for (int j = 0; j < 4; ++j) {
        int n = n0 + j * 16 + fr;
        float bvv = bias[n];
#pragma unroll
        for (int r = 0; r < 4; ++r) {
            int m = m0 + w * 16 + r0 + r;
            float val = accs[j][r] + bvv;
            if (!isV) {
                Kout[(size_t)m * N + n] = f2bf(val);
            } else {
                int bb = m >> 10, c = m & (P_ - 1);
                int hh = n >> 6, d = n & 63;
                Vout[(((size_t)(bb * H_ + hh)) * 64 + d) * P_ + c] = f2bf(val);
            }
        }
    }
}

// ---------------------------------------------------------------------------
// 128x128-tile GEMM, global_load_lds staging (m97 recipe), BK=32, 4 waves.
// MODE 0: fp32 out.  MODE 3: bf16 out scaled by KSCALE (Q projection).
// ---------------------------------------------------------------------------
template <int MODE>
__global__ __launch_bounds__(256) void xattn_gemm128(
    const unsigned short* __restrict__ A,
    const unsigned short* __restrict__ W,
    const float* __restrict__ bias,
    void* __restrict__ Cout, int M) {
    const int K = 1024, N = 1024;
    __shared__ unsigned short As[128 * 32];
    __shared__ unsigned short Bs[128 * 32];

    const int m0 = blockIdx.y * 128;
    const int n0 = blockIdx.x * 128;
    const int t = threadIdx.x;
    const int w = t >> 6;
    const int l = t & 63;
    const int fr = l & 15, fq = l >> 4;
    const int wr = w >> 1, wc = w & 1;

    const int r0s = t >> 2;
    const int cs = (t & 3) * 8;
    const unsigned short* Ap0 = A + (size_t)(m0 + r0s) * K + cs;
    const unsigned short* Ap1 = A + (size_t)(m0 + 64 + r0s) * K + cs;
    const unsigned short* Wp0 = W + (size_t)(n0 + r0s) * K + cs;
    const unsigned short* Wp1 = W + (size_t)(n0 + 64 + r0s) * K + cs;
    const unsigned short* lA0 = &As[(w * 64) * 8];
    const unsigned short* lA1 = &As[(256 + w * 64) * 8];
    const unsigned short* lB0 = &Bs[(w * 64) * 8];
    const unsigned short* lB1 = &Bs[(256 + w * 64) * 8];

    f32x4 acc[4][4];
#pragma unroll
    for (int i = 0; i < 4; ++i)
#pragma unroll
        for (int j = 0; j < 4; ++j) acc[i][j] = (f32x4){0.f, 0.f, 0.f, 0.f};

    for (int k0 = 0; k0 < K; k0 += 32) {
        gll16(Ap0 + k0, lA0);
        gll16(Ap1 + k0, lA1);
        gll16(Wp0 + k0, lB0);
        gll16(Wp1 + k0, lB1);
        __syncthreads();
        short8 af[4], bf[4];
#pragma unroll
        for (int i = 0; i < 4; ++i)
            af[i] = *(const short8*)&As[(wr * 64 + i * 16 + fr) * 32 + fq * 8];
#pragma unroll
        for (int j = 0; j < 4; ++j)
            bf[j] = *(const short8*)&Bs[(wc * 64 + j * 16 + fr) * 32 + fq * 8];
#pragma unroll
        for (int i = 0; i < 4; ++i)
#pragma unroll
            for (int j = 0; j < 4; ++j)
                acc[i][j] = __builtin_amdgcn_mfma_f32_16x16x32_bf16(af[i], bf[j], acc[i][j], 0, 0, 0);
        __syncthreads();
    }

#pragma unroll
    for (int j = 0; j < 4; ++j) {
        int n = n0 + wc * 64 + j * 16 + fr;
        float bv = bias[n];
#pragma unroll
        for (int i = 0; i < 4; ++i) {
            int mbase = m0 + wr * 64 + i * 16 + fq * 4;
#pragma unroll
            for (int r = 0; r < 4; ++r) {
                float val = acc[i][j][r] + bv;
                if (MODE == 0) {
                    ((float*)Cout)[(size_t)(mbase + r) * N + n] = val;
                } else {
                    ((unsigned short*)Cout)[(size_t)(mbase + r) * N + n] = f2bf(val * KSCALE);
                }
            }
        }
    }
}

// ---------------------------------------------------------------------------
// MFMA flash attention (R3 orientation, 128 q-rows per block).
// Block = 4 waves; wave w owns q-rows {s*64 + w*16 + [0,16) : s in 0,1}.
// Per 64-col K-tile:
//   QK^T: Q frags in regs, K tile LDS [64][72]; kf reads shared by strips.
//   exp2 (shift-invariant; Q pre-scaled) fused per-fragment, P scatter to
//   Ps[128][72] (same-wave rows), PV via 2x MFMA32 per (strip, nt).
// Prefix mask monotone -> boundary-only masking + per-block tile early-exit.
// ---------------------------------------------------------------------------
__global__ __launch_bounds__(256) void xattn_attn_mfma(
    const unsigned short* __restrict__ Qb,   // [B*S][D] bf16 (pre-scaled)
    const unsigned short* __restrict__ Kb,   // [B*P][D] bf16
    const unsigned short* __restrict__ Vtb,  // [B][H][64][P] bf16
    const int* __restrict__ pidx,
    unsigned short* __restrict__ Ob) {       // [B*S][D] bf16
    __shared__ unsigned short Ks[64 * 72];
    __shared__ unsigned short Vs[64 * 72];
    __shared__ unsigned short Ps[128 * 72];

    const int q0 = (S_ / 128 - 1 - blockIdx.x) * 128;  // LPT: heavy blocks first
    const int h = blockIdx.y;
    const int b = blockIdx.z;
    const int t = threadIdx.x;
    const int w = t >> 6, l = t & 63;
    const int fr = l & 15, fq = l >> 4;

    // Q A-frags for 2 strips: row = q0 + s*64 + w*16 + fr, k = fq*8 (+32)
    short8 qf[2][2];
    {
        const unsigned short* qbase =
            Qb + (size_t)(b * S_ + q0 + w * 16 + fr) * D_ + h * DH_ + fq * 8;
        qf[0][0] = *(const short8*)qbase;
        qf[0][1] = *(const short8*)(qbase + 32);
        qf[1][0] = *(const short8*)(qbase + (size_t)64 * D_);
        qf[1][1] = *(const short8*)(qbase + (size_t)64 * D_ + 32);
    }
    int prow[2][4];
#pragma unroll
    for (int s = 0; s < 2; ++s)
#pragma unroll
        for (int r = 0; r < 4; ++r)
            prow[s][r] = pidx[b * S_ + q0 + s * 64 + w * 16 + fq * 4 + r];
    const int limit = pidx[b * S_ + q0 + 127];      // monotone in s
    const int ntiles = (min(limit, P_ - 1) + 64) >> 6;
    const int nfull = (pidx[b * S_ + q0] + 1) >> 6; // tiles needing no mask

    float lsum[2][4] = {{0.f, 0.f, 0.f, 0.f}, {0.f, 0.f, 0.f, 0.f}};
    f32x4 oacc[2][4];   // [strip][nt]
#pragma unroll
    for (int s = 0; s < 2; ++s)
#pragma unroll
        for (int nt = 0; nt < 4; ++nt) oacc[s][nt] = (f32x4){0.f, 0.f, 0.f, 0.f};

    const int srow = t >> 3, sseg = t & 7;
    const unsigned short* kbase = Kb + (size_t)(b * P_) * D_ + h * DH_;
    const unsigned short* vbase = Vtb + (size_t)(b * H_ + h) * 64 * P_;

    for (int kt = 0; kt < ntiles; ++kt) {
        const int c0 = kt * 64;
        __syncthreads();   // protect LDS from previous tile's readers
        *(uint4*)&Ks[srow * 72 + sseg * 8] =
            *(const uint4*)(kbase + (size_t)(c0 + srow) * D_ + sseg * 8);
        *(uint4*)&Ks[(srow + 32) * 72 + sseg * 8] =
            *(const uint4*)(kbase + (size_t)(c0 + srow + 32) * D_ + sseg * 8);
        *(uint4*)&Vs[srow * 72 + sseg * 8] =
            *(const uint4*)(vbase + (size_t)srow * P_ + c0 + sseg * 8);
        *(uint4*)&Vs[(srow + 32) * 72 + sseg * 8] =
            *(const uint4*)(vbase + (size_t)(srow + 32) * P_ + c0 + sseg * 8);
        __syncthreads();

        const int maskme = (kt >= nfull);
        // QK^T + exp2 + scatter, strip-inner so only one f32x4 stays live
#pragma unroll
        for (int nt = 0; nt < 4; ++nt) {
            short8 kf0 = *(const short8*)&Ks[(nt * 16 + fr) * 72 + fq * 8];
            short8 kf1 = *(const short8*)&Ks[(nt * 16 + fr) * 72 + 32 + fq * 8];
            const int col = c0 + nt * 16 + fr;
#pragma unroll
            for (int s = 0; s < 2; ++s) {
                f32x4 a = (f32x4){0.f, 0.f, 0.f, 0.f};
                a = __builtin_amdgcn_mfma_f32_16x16x32_bf16(qf[s][0], kf0, a, 0, 0, 0);
                a = __builtin_amdgcn_mfma_f32_16x16x32_bf16(qf[s][1], kf1, a, 0, 0, 0);
#pragma unroll
                for (int r = 0; r < 4; ++r) {
                    float p = exp2f(a[r]);
                    if (maskme) p = (col > prow[s][r]) ? 0.f : p;
                    lsum[s][r] += p;
                    Ps[(s * 64 + w * 16 + fq * 4 + r) * 72 + nt * 16 + fr] = f2bf(p);
                }
            }
        }
        // PV: O[q][d] += P[q][c] V[c][d]; A=P rows, B=V^T rows, K=64 (2 halves)
#pragma unroll
        for (int s = 0; s < 2; ++s) {
            short8 pf0 = *(const short8*)&Ps[(s * 64 + w * 16 + fr) * 72 + fq * 8];
            short8 pf1 = *(const short8*)&Ps[(s * 64 + w * 16 + fr) * 72 + 32 + fq * 8];
#pragma unroll
            for (int nt = 0; nt < 4; ++nt) {
                short8 vf0 = *(const short8*)&Vs[(nt * 16 + fr) * 72 + fq * 8];
                short8 vf1 = *(const short8*)&Vs[(nt * 16 + fr) * 72 + 32 + fq * 8];
                oacc[s][nt] = __builtin_amdgcn_mfma_f32_16x16x32_bf16(pf0, vf0, oacc[s][nt], 0, 0, 0);
                oacc[s][nt] = __builtin_amdgcn_mfma_f32_16x16x32_bf16(pf1, vf1, oacc[s][nt], 0, 0, 0);
            }
        }
    }

    // l reduction across the 16 fr lanes of each quad-group
#pragma unroll
    for (int off = 1; off < 16; off <<= 1) {
#pragma unroll
        for (int s = 0; s < 2; ++s)
#pragma unroll
            for (int r = 0; r < 4; ++r)
                lsum[s][r] += __shfl_xor(lsum[s][r], off);
    }
#pragma unroll
    for (int s = 0; s < 2; ++s) {
        float inv[4];
#pragma unroll
        for (int r = 0; r < 4; ++r) inv[r] = 1.0f / lsum[s][r];
        unsigned short* obase =
            Ob + (size_t)(b * S_ + q0 + s * 64 + w * 16) * D_ + h * DH_;
#pragma unroll
        for (int nt = 0; nt < 4; ++nt)
#pragma unroll
            for (int r = 0; r < 4; ++r)
                obase[(size_t)(fq * 4 + r) * D_ + nt * 16 + fr] =
                    f2bf(oacc[s][nt][r] * inv[r]);
    }
}

// ---------------------------------------------------------------------------
// launch
// ---------------------------------------------------------------------------
extern "C" void kernel_launch(void* const* d_in, const int* in_sizes, int n_in,
                              void* d_out, int out_size, void* d_ws, size_t ws_size,
                              hipStream_t stream) {
    const float* queries = (const float*)d_in[0];
    const float* patches = (const float*)d_in[1];
    const int* bounds    = (const int*)d_in[2];
    const float* wq = (const float*)d_in[3];
    const float* wk = (const float*)d_in[4];
    const float* wv = (const float*)d_in[5];
    const float* wo = (const float*)d_in[6];
    const float* bq = (const float*)d_in[7];
    const float* bk = (const float*)d_in[8];
    const float* bv = (const float*)d_in[9];
    const float* bo = (const float*)d_in[10];
    float* out = (float*)d_out;

    char* ws = (char*)d_ws;
    unsigned short* qb    = (unsigned short*)(ws + 0);          // 16777216
    unsigned short* pb    = (unsigned short*)(ws + 16777216);   // 4194304
    unsigned short* wqb   = (unsigned short*)(ws + 20971520);   // 2097152
    unsigned short* wkb   = (unsigned short*)(ws + 23068672);
    unsigned short* wvb   = (unsigned short*)(ws + 25165824);
    unsigned short* wob   = (unsigned short*)(ws + 27262976);
    unsigned short* Qbf   = (unsigned short*)(ws + 29360128);   // 16777216
    unsigned short* Kbf   = (unsigned short*)(ws + 46137344);   // 4194304
    unsigned short* Vtb   = (unsigned short*)(ws + 50331648);   // 4194304
    unsigned short* attnb = (unsigned short*)(ws + 54525952);   // 16777216
    int* pidx             = (int*)(ws + 71303168);              // 32768

    // 1. fused converts + cumsum (NCONV convert blocks + B_ cumsum blocks)
    xattn_convert_all<<<dim3(NCONV + B_), 256, 0, stream>>>(
        queries, patches, wq, wk, wv, wo, qb, pb, wqb, wkb, wvb, wob,
        bounds, pidx);
    // 2. projections
    xattn_gemm128<3><<<dim3(8, 64), 256, 0, stream>>>(qb, wqb, bq, (void*)Qbf, B_ * S_);
    xattn_gemm_kv<<<dim3(16, 32, 2), 256, 0, stream>>>(pb, wkb, wvb, bk, bv, Kbf, Vtb);
    // 3. MFMA flash attention (128 q-rows per block)
    xattn_attn_mfma<<<dim3(S_ / 128, H_, B_), 256, 0, stream>>>(Qbf, Kbf, Vtb, pidx, attnb);
    // 4. output projection (fp32 out)
    xattn_gemm128<0><<<dim3(8, 64), 256, 0, stream>>>(attnb, wob, bo, out, B_ * S_);
}

// Round 6
// 266.949 us; speedup vs baseline: 1.1477x; 1.1268x over previous
//
#include <hip/hip_runtime.h>

// ---------------------------------------------------------------------------
// CrossAttention (BLT-style patch cross-attention), MI355X gfx950
// B=2, S=4096, P=1024, D=1024, H=16, dh=64
//
// Round 6:
//   - attention: R3 64-row structure (2048 blocks, 5/CU) + REGISTER PREFETCH
//     of next K/V tile (global->VGPR during compute, ds_write after barrier)
//     to take global latency off the per-tile dependency chain.
//   - Q/K/V projections fused into ONE 128-tile gll GEMM launch (z selects
//     output mode: Q bf16*KSCALE / K bf16 / V bf16 transposed per-head).
// ---------------------------------------------------------------------------

#define B_ 2
#define S_ 4096
#define P_ 1024
#define D_ 1024
#define H_ 16
#define DH_ 64

#define NCONV 14336   /* convert blocks: (2097152+524288+4*262144)/256 */

typedef __attribute__((ext_vector_type(8))) short short8;
typedef __attribute__((ext_vector_type(4))) float f32x4;

#define KSCALE 0.18033688011112042f  /* 1/sqrt(64) * log2(e) */

static __device__ __forceinline__ unsigned short f2bf(float f) {
    unsigned int u = __float_as_uint(f);
    u += 0x7FFFu + ((u >> 16) & 1u);   // round-to-nearest-even
    return (unsigned short)(u >> 16);
}

// async 16B global -> LDS (wave-uniform lds base + lane*16)
static __device__ __forceinline__ void gll16(const unsigned short* g,
                                             const unsigned short* l) {
    __builtin_amdgcn_global_load_lds(
        (const __attribute__((address_space(1))) unsigned int*)g,
        (__attribute__((address_space(3))) unsigned int*)l,
        16, 0, 0);
}

// ---------------------------------------------------------------------------
// fused fp32 -> bf16 conversion of all six tensors + cumsum (single launch)
// ---------------------------------------------------------------------------
__global__ __launch_bounds__(256) void xattn_convert_all(
    const float* __restrict__ queries, const float* __restrict__ patches,
    const float* __restrict__ wq, const float* __restrict__ wk,
    const float* __restrict__ wv, const float* __restrict__ wo,
    unsigned short* __restrict__ qb, unsigned short* __restrict__ pb,
    unsigned short* __restrict__ wqb, unsigned short* __restrict__ wkb,
    unsigned short* __restrict__ wvb, unsigned short* __restrict__ wob,
    const int* __restrict__ bounds, int* __restrict__ pidx) {
    if (blockIdx.x >= NCONV) {
        // ---- cumsum path: one block per batch, 256 threads x 16 elems ----
        __shared__ int sdata[256];
        int b = blockIdx.x - NCONV;
        int t = threadIdx.x;
        const int* src = bounds + b * S_ + t * 16;
        int vals[16];
        int run = 0;
#pragma unroll
        for (int i = 0; i < 16; ++i) { run += src[i]; vals[i] = run; }
        sdata[t] = run;
        __syncthreads();
        for (int off = 1; off < 256; off <<= 1) {
            int v = (t >= off) ? sdata[t - off] : 0;
            __syncthreads();
            sdata[t] += v;
            __syncthreads();
        }
        int prefix = (t > 0) ? sdata[t - 1] : 0;
        int* dst = pidx + b * S_ + t * 16;
#pragma unroll
        for (int i = 0; i < 16; ++i) dst[i] = prefix + vals[i];
        return;
    }
    // ---- convert path ----
    const int NQ = (B_ * S_ * D_) / 4;      // 2097152
    const int NP = (B_ * P_ * D_) / 4;      // 524288
    const int NW = (D_ * D_) / 4;           // 262144
    int i = blockIdx.x * 256 + threadIdx.x;
    const float* src;
    unsigned short* dst;
    int j;
    if (i < NQ) { src = queries; dst = qb; j = i; }
    else if (i < NQ + NP) { src = patches; dst = pb; j = i - NQ; }
    else {
        int k = i - NQ - NP;
        int wsel = k >> 18;                  // NW = 2^18
        j = k & (NW - 1);
        if (wsel == 0) { src = wq; dst = wqb; }
        else if (wsel == 1) { src = wk; dst = wkb; }
        else if (wsel == 2) { src = wv; dst = wvb; }
        else { src = wo; dst = wob; }
    }
    float4 v = ((const float4*)src)[j];
    ushort4 o;
    o.x = f2bf(v.x); o.y = f2bf(v.y); o.z = f2bf(v.z); o.w = f2bf(v.w);
    ((ushort4*)dst)[j] = o;
}

// ---------------------------------------------------------------------------
// Fused QKV projection: 128x128 tile, global_load_lds staging, BK=32, 4 waves.
// blockIdx.z: 0 = Q-proj (M=8192, bf16 out * KSCALE)
//             1 = K-proj (M=2048, bf16 out)         [by < 16]
//             2 = V-proj (M=2048, bf16 transposed)  [by < 16]
// ---------------------------------------------------------------------------
__global__ __launch_bounds__(256) void xattn_gemm_qkv(
    const unsigned short* __restrict__ qb, const unsigned short* __restrict__ pb,
    const unsigned short* __restrict__ wqb, const unsigned short* __restrict__ wkb,
    const unsigned short* __restrict__ wvb,
    const float* __restrict__ bq, const float* __restrict__ bk,
    const float* __restrict__ bv,
    unsigned short* __restrict__ Qout, unsigned short* __restrict__ Kout,
    unsigned short* __restrict__ Vout) {
    const int K = 1024, N = 1024;
    const int z = blockIdx.z;
    if (z > 0 && blockIdx.y >= 16) return;
    const unsigned short* A = (z == 0) ? qb : pb;
    const unsigned short* W = (z == 0) ? wqb : ((z == 1) ? wkb : wvb);
    const float* bias = (z == 0) ? bq : ((z == 1) ? bk : bv);

    __shared__ unsigned short As[128 * 32];
    __shared__ unsigned short Bs[128 * 32];

    const int m0 = blockIdx.y * 128;
    const int n0 = blockIdx.x * 128;
    const int t = threadIdx.x;
    const int w = t >> 6;
    const int l = t & 63;
    const int fr = l & 15, fq = l >> 4;
    const int wr = w >> 1, wc = w & 1;

    const int r0s = t >> 2;
    const int cs = (t & 3) * 8;
    const unsigned short* Ap0 = A + (size_t)(m0 + r0s) * K + cs;
    const unsigned short* Ap1 = A + (size_t)(m0 + 64 + r0s) * K + cs;
    const unsigned short* Wp0 = W + (size_t)(n0 + r0s) * K + cs;
    const unsigned short* Wp1 = W + (size_t)(n0 + 64 + r0s) * K + cs;
    const unsigned short* lA0 = &As[(w * 64) * 8];
    const unsigned short* lA1 = &As[(256 + w * 64) * 8];
    const unsigned short* lB0 = &Bs[(w * 64) * 8];
    const unsigned short* lB1 = &Bs[(256 + w * 64) * 8];

    f32x4 acc[4][4];
#pragma unroll
    for (int i = 0; i < 4; ++i)
#pragma unroll
        for (int j = 0; j < 4; ++j) acc[i][j] = (f32x4){0.f, 0.f, 0.f, 0.f};

    for (int k0 = 0; k0 < K; k0 += 32) {
        gll16(Ap0 + k0, lA0);
        gll16(Ap1 + k0, lA1);
        gll16(Wp0 + k0, lB0);
        gll16(Wp1 + k0, lB1);
        __syncthreads();
        short8 af[4], bf[4];
#pragma unroll
        for (int i = 0; i < 4; ++i)
            af[i] = *(const short8*)&As[(wr * 64 + i * 16 + fr) * 32 + fq * 8];
#pragma unroll
        for (int j = 0; j < 4; ++j)
            bf[j] = *(const short8*)&Bs[(wc * 64 + j * 16 + fr) * 32 + fq * 8];
#pragma unroll
        for (int i = 0; i < 4; ++i)
#pragma unroll
            for (int j = 0; j < 4; ++j)
                acc[i][j] = __builtin_amdgcn_mfma_f32_16x16x32_bf16(af[i], bf[j], acc[i][j], 0, 0, 0);
        __syncthreads();
    }

#pragma unroll
    for (int j = 0; j < 4; ++j) {
        int n = n0 + wc * 64 + j * 16 + fr;
        float bvv = bias[n];
#pragma unroll
        for (int i = 0; i < 4; ++i) {
            int mbase = m0 + wr * 64 + i * 16 + fq * 4;
#pragma unroll
            for (int r = 0; r < 4; ++r) {
                float val = acc[i][j][r] + bvv;
                int m = mbase + r;
                if (z == 0) {
                    Qout[(size_t)m * N + n] = f2bf(val * KSCALE);
                } else if (z == 1) {
                    Kout[(size_t)m * N + n] = f2bf(val);
                } else {
                    int bb = m >> 10, c = m & (P_ - 1);
                    int hh = n >> 6, d = n & 63;
                    Vout[(((size_t)(bb * H_ + hh)) * 64 + d) * P_ + c] = f2bf(val);
                }
            }
        }
    }
}

// ---------------------------------------------------------------------------
// 128x128-tile GEMM, global_load_lds staging, fp32 out (O projection).
// ---------------------------------------------------------------------------
__global__ __launch_bounds__(256) void xattn_gemm_o(
    const unsigned short* __restrict__ A,
    const unsigned short* __restrict__ W,
    const float* __restrict__ bias,
    float* __restrict__ Cout) {
    const int K = 1024, N = 1024;
    __shared__ unsigned short As[128 * 32];
    __shared__ unsigned short Bs[128 * 32];

    const int m0 = blockIdx.y * 128;
    const int n0 = blockIdx.x * 128;
    const int t = threadIdx.x;
    const int w = t >> 6;
    const int l = t & 63;
    const int fr = l & 15, fq = l >> 4;
    const int wr = w >> 1, wc = w & 1;

    const int r0s = t >> 2;
    const int cs = (t & 3) * 8;
    const unsigned short* Ap0 = A + (size_t)(m0 + r0s) * K + cs;
    const unsigned short* Ap1 = A + (size_t)(m0 + 64 + r0s) * K + cs;
    const unsigned short* Wp0 = W + (size_t)(n0 + r0s) * K + cs;
    const unsigned short* Wp1 = W + (size_t)(n0 + 64 + r0s) * K + cs;
    const unsigned short* lA0 = &As[(w * 64) * 8];
    const unsigned short* lA1 = &As[(256 + w * 64) * 8];
    const unsigned short* lB0 = &Bs[(w * 64) * 8];
    const unsigned short* lB1 = &Bs[(256 + w * 64) * 8];

    f32x4 acc[4][4];
#pragma unroll
    for (int i = 0; i < 4; ++i)
#pragma unroll
        for (int j = 0; j < 4; ++j) acc[i][j] = (f32x4){0.f, 0.f, 0.f, 0.f};

    for (int k0 = 0; k0 < K; k0 += 32) {
        gll16(Ap0 + k0, lA0);
        gll16(Ap1 + k0, lA1);
        gll16(Wp0 + k0, lB0);
        gll16(Wp1 + k0, lB1);
        __syncthreads();
        short8 af[4], bf[4];
#pragma unroll
        for (int i = 0; i < 4; ++i)
            af[i] = *(const short8*)&As[(wr * 64 + i * 16 + fr) * 32 + fq * 8];
#pragma unroll
        for (int j = 0; j < 4; ++j)
            bf[j] = *(const short8*)&Bs[(wc * 64 + j * 16 + fr) * 32 + fq * 8];
#pragma unroll
        for (int i = 0; i < 4; ++i)
#pragma unroll
            for (int j = 0; j < 4; ++j)
                acc[i][j] = __builtin_amdgcn_mfma_f32_16x16x32_bf16(af[i], bf[j], acc[i][j], 0, 0, 0);
        __syncthreads();
    }

#pragma unroll
    for (int j = 0; j < 4; ++j) {
        int n = n0 + wc * 64 + j * 16 + fr;
        float bvv = bias[n];
#pragma unroll
        for (int i = 0; i < 4; ++i) {
            int mbase = m0 + wr * 64 + i * 16 + fq * 4;
#pragma unroll
            for (int r = 0; r < 4; ++r)
                Cout[(size_t)(mbase + r) * N + n] = acc[i][j][r] + bvv;
        }
    }
}

// ---------------------------------------------------------------------------
// MFMA flash attention (R3 structure + register prefetch of next K/V tile).
// Block = 4 waves, 64 q-rows. Per tile: QK^T (MFMA32, K LDS), exp2
// (shift-invariant, Q pre-scaled), P scatter (same-wave), PV (MFMA32, V LDS).
// Next tile's K/V loaded into VGPRs during compute; ds_write after barrier.
// ---------------------------------------------------------------------------
__global__ __launch_bounds__(256) void xattn_attn_mfma(
    const unsigned short* __restrict__ Qb,   // [B*S][D] bf16 (pre-scaled)
    const unsigned short* __restrict__ Kb,   // [B*P][D] bf16
    const unsigned short* __restrict__ Vtb,  // [B][H][64][P] bf16
    const int* __restrict__ pidx,
    unsigned short* __restrict__ Ob) {       // [B*S][D] bf16
    __shared__ unsigned short Ks[64 * 72];
    __shared__ unsigned short Vs[64 * 72];
    __shared__ unsigned short Ps[64 * 72];

    const int q0 = (63 - blockIdx.x) * 64;   // LPT: heavy blocks dispatch first
    const int h = blockIdx.y;
    const int b = blockIdx.z;
    const int t = threadIdx.x;
    const int w = t >> 6, l = t & 63;
    const int fr = l & 15, fq = l >> 4;

    // Q A-frags, loaded once
    const unsigned short* qrow =
        Qb + (size_t)(b * S_ + q0 + w * 16 + fr) * D_ + h * DH_ + fq * 8;
    short8 qf0 = *(const short8*)qrow;
    short8 qf1 = *(const short8*)(qrow + 32);

    int prow[4];
#pragma unroll
    for (int r = 0; r < 4; ++r)
        prow[r] = pidx[b * S_ + q0 + w * 16 + fq * 4 + r];
    const int limit = pidx[b * S_ + q0 + 63];       // monotone in s
    const int ntiles = (min(limit, P_ - 1) + 64) >> 6;
    const int nfull = (pidx[b * S_ + q0] + 1) >> 6; // tiles needing no mask

    float lsum[4] = {0.f, 0.f, 0.f, 0.f};
    f32x4 oacc[4];
#pragma unroll
    for (int nt = 0; nt < 4; ++nt) oacc[nt] = (f32x4){0.f, 0.f, 0.f, 0.f};

    const int srow = t >> 3, sseg = t & 7;
    const unsigned short* kbase = Kb + (size_t)(b * P_) * D_ + h * DH_;
    const unsigned short* vbase = Vtb + (size_t)(b * H_ + h) * 64 * P_;
    unsigned short* ksa = &Ks[srow * 72 + sseg * 8];
    unsigned short* ksb = &Ks[(srow + 32) * 72 + sseg * 8];
    unsigned short* vsa = &Vs[srow * 72 + sseg * 8];
    unsigned short* vsb = &Vs[(srow + 32) * 72 + sseg * 8];

    // prologue: tile 0 -> regs -> LDS
    uint4 rk0 = *(const uint4*)(kbase + (size_t)srow * D_ + sseg * 8);
    uint4 rk1 = *(const uint4*)(kbase + (size_t)(srow + 32) * D_ + sseg * 8);
    uint4 rv0 = *(const uint4*)(vbase + (size_t)srow * P_ + sseg * 8);
    uint4 rv1 = *(const uint4*)(vbase + (size_t)(srow + 32) * P_ + sseg * 8);
    *(uint4*)ksa = rk0;
    *(uint4*)ksb = rk1;
    *(uint4*)vsa = rv0;
    *(uint4*)vsb = rv1;
    __syncthreads();

    for (int kt = 0; kt < ntiles; ++kt) {
        const int c0 = kt * 64;
        // prefetch next tile into registers (clamped; unused on last iter)
        const int c0n = min(c0 + 64, P_ - 64);
        rk0 = *(const uint4*)(kbase + (size_t)(c0n + srow) * D_ + sseg * 8);
        rk1 = *(const uint4*)(kbase + (size_t)(c0n + srow + 32) * D_ + sseg * 8);
        rv0 = *(const uint4*)(vbase + (size_t)srow * P_ + c0n + sseg * 8);
        rv1 = *(const uint4*)(vbase + (size_t)(srow + 32) * P_ + c0n + sseg * 8);

        const int maskme = (kt >= nfull);
        // QK^T + exp2 + scatter
#pragma unroll
        for (int nt = 0; nt < 4; ++nt) {
            short8 kf0 = *(const short8*)&Ks[(nt * 16 + fr) * 72 + fq * 8];
            short8 kf1 = *(const short8*)&Ks[(nt * 16 + fr) * 72 + 32 + fq * 8];
            const int col = c0 + nt * 16 + fr;
            f32x4 a = (f32x4){0.f, 0.f, 0.f, 0.f};
            a = __builtin_amdgcn_mfma_f32_16x16x32_bf16(qf0, kf0, a, 0, 0, 0);
            a = __builtin_amdgcn_mfma_f32_16x16x32_bf16(qf1, kf1, a, 0, 0, 0);
#pragma unroll
            for (int r = 0; r < 4; ++r) {
                float p = exp2f(a[r]);
                if (maskme) p = (col > prow[r]) ? 0.f : p;
                lsum[r] += p;
                Ps[(w * 16 + fq * 4 + r) * 72 + nt * 16 + fr] = f2bf(p);
            }
        }
        // PV (A = P rows, B = V^T rows, K = 64 in 2 halves)
        short8 pf0 = *(const short8*)&Ps[(w * 16 + fr) * 72 + fq * 8];
        short8 pf1 = *(const short8*)&Ps[(w * 16 + fr) * 72 + 32 + fq * 8];
#pragma unroll
        for (int nt = 0; nt < 4; ++nt) {
            short8 vf0 = *(const short8*)&Vs[(nt * 16 + fr) * 72 + fq * 8];
            short8 vf1 = *(const short8*)&Vs[(nt * 16 + fr) * 72 + 32 + fq * 8];
            oacc[nt] = __builtin_amdgcn_mfma_f32_16x16x32_bf16(pf0, vf0, oacc[nt], 0, 0, 0);
            oacc[nt] = __builtin_amdgcn_mfma_f32_16x16x32_bf16(pf1, vf1, oacc[nt], 0, 0, 0);
        }
        __syncthreads();   // all waves done reading Ks/Vs of tile kt
        *(uint4*)ksa = rk0;
        *(uint4*)ksb = rk1;
        *(uint4*)vsa = rv0;
        *(uint4*)vsb = rv1;
        __syncthreads();   // tile kt+1 visible
    }

    // l reduction across the 16 fr lanes of each quad-group
#pragma unroll
    for (int off = 1; off < 16; off <<= 1) {
#pragma unroll
        for (int r = 0; r < 4; ++r)
            lsum[r] += __shfl_xor(lsum[r], off);
    }
    float inv[4];
#pragma unroll
    for (int r = 0; r < 4; ++r) inv[r] = 1.0f / lsum[r];

    unsigned short* obase = Ob + (size_t)(b * S_ + q0 + w * 16) * D_ + h * DH_;
#pragma unroll
    for (int nt = 0; nt < 4; ++nt)
#pragma unroll
        for (int r = 0; r < 4; ++r)
            obase[(size_t)(fq * 4 + r) * D_ + nt * 16 + fr] =
                f2bf(oacc[nt][r] * inv[r]);
}

// ---------------------------------------------------------------------------
// launch
// ---------------------------------------------------------------------------
extern "C" void kernel_launch(void* const* d_in, const int* in_sizes, int n_in,
                              void* d_out, int out_size, void* d_ws, size_t ws_size,
                              hipStream_t stream) {
    const float* queries = (const float*)d_in[0];
    const float* patches = (const float*)d_in[1];
    const int* bounds    = (const int*)d_in[2];
    const float* wq = (const float*)d_in[3];
    const float* wk = (const float*)d_in[4];
    const float* wv = (const float*)d_in[5];
    const float* wo = (const float*)d_in[6];
    const float* bq = (const float*)d_in[7];
    const float* bk = (const float*)d_in[8];
    const float* bv = (const float*)d_in[9];
    const float* bo = (const float*)d_in[10];
    float* out = (float*)d_out;

    char* ws = (char*)d_ws;
    unsigned short* qb    = (unsigned short*)(ws + 0);          // 16777216
    unsigned short* pb    = (unsigned short*)(ws + 16777216);   // 4194304
    unsigned short* wqb   = (unsigned short*)(ws + 20971520);   // 2097152
    unsigned short* wkb   = (unsigned short*)(ws + 23068672);
    unsigned short* wvb   = (unsigned short*)(ws + 25165824);
    unsigned short* wob   = (unsigned short*)(ws + 27262976);
    unsigned short* Qbf   = (unsigned short*)(ws + 29360128);   // 16777216
    unsigned short* Kbf   = (unsigned short*)(ws + 46137344);   // 4194304
    unsigned short* Vtb   = (unsigned short*)(ws + 50331648);   // 4194304
    unsigned short* attnb = (unsigned short*)(ws + 54525952);   // 16777216
    int* pidx             = (int*)(ws + 71303168);              // 32768

    // 1. fused converts + cumsum
    xattn_convert_all<<<dim3(NCONV + B_), 256, 0, stream>>>(
        queries, patches, wq, wk, wv, wo, qb, pb, wqb, wkb, wvb, wob,
        bounds, pidx);
    // 2. fused Q/K/V projections (one launch)
    xattn_gemm_qkv<<<dim3(8, 64, 3), 256, 0, stream>>>(
        qb, pb, wqb, wkb, wvb, bq, bk, bv, Qbf, Kbf, Vtb);
    // 3. MFMA flash attention (reg-prefetch dbuf)
    xattn_attn_mfma<<<dim3(S_ / 64, H_, B_), 256, 0, stream>>>(
        Qbf, Kbf, Vtb, pidx, attnb);
    // 4. output projection (fp32 out)
    xattn_gemm_o<<<dim3(8, 64), 256, 0, stream>>>(attnb, wob, bo, out);
}

// Round 7
// 245.418 us; speedup vs baseline: 1.2484x; 1.0877x over previous
//
#include <hip/hip_runtime.h>

// ---------------------------------------------------------------------------
// CrossAttention (BLT-style patch cross-attention), MI355X gfx950
// B=2, S=4096, P=1024, D=1024, H=16, dh=64
//
// Round 7 (attention issue-count reduction):
//   - raw v_exp_f32 (no ocml guard), scores bounded
//   - P packed by v_perm_b32 truncation (2 vals/instr)
//   - sigma-permuted PV k-dimension: sigma(c)=(c%16)*4+c/16 applied to BOTH
//     P columns and V rows (permutation-invariant contraction) ->
//     P written as 4x ds_write_b64 (conflict-free) instead of 16x ds_write_b16
//   - staging reverted to R3 pattern (no reg prefetch; it measured -8%)
//   - keep: fused convert+cumsum, fused QKV GEMM, gll 128-tile GEMMs
// ---------------------------------------------------------------------------

#define B_ 2
#define S_ 4096
#define P_ 1024
#define D_ 1024
#define H_ 16
#define DH_ 64

#define NCONV 14336   /* convert blocks: (2097152+524288+4*262144)/256 */

typedef __attribute__((ext_vector_type(8))) short short8;
typedef __attribute__((ext_vector_type(4))) float f32x4;

#define KSCALE 0.18033688011112042f  /* 1/sqrt(64) * log2(e) */

#if __has_builtin(__builtin_amdgcn_exp2f)
#define EXP2(x) __builtin_amdgcn_exp2f(x)
#else
#define EXP2(x) exp2f(x)
#endif

static __device__ __forceinline__ unsigned short f2bf(float f) {
    unsigned int u = __float_as_uint(f);
    u += 0x7FFFu + ((u >> 16) & 1u);   // round-to-nearest-even
    return (unsigned short)(u >> 16);
}

// async 16B global -> LDS (wave-uniform lds base + lane*16)
static __device__ __forceinline__ void gll16(const unsigned short* g,
                                             const unsigned short* l) {
    __builtin_amdgcn_global_load_lds(
        (const __attribute__((address_space(1))) unsigned int*)g,
        (__attribute__((address_space(3))) unsigned int*)l,
        16, 0, 0);
}

// ---------------------------------------------------------------------------
// fused fp32 -> bf16 conversion of all six tensors + cumsum (single launch)
// ---------------------------------------------------------------------------
__global__ __launch_bounds__(256) void xattn_convert_all(
    const float* __restrict__ queries, const float* __restrict__ patches,
    const float* __restrict__ wq, const float* __restrict__ wk,
    const float* __restrict__ wv, const float* __restrict__ wo,
    unsigned short* __restrict__ qb, unsigned short* __restrict__ pb,
    unsigned short* __restrict__ wqb, unsigned short* __restrict__ wkb,
    unsigned short* __restrict__ wvb, unsigned short* __restrict__ wob,
    const int* __restrict__ bounds, int* __restrict__ pidx) {
    if (blockIdx.x >= NCONV) {
        // ---- cumsum path: one block per batch, 256 threads x 16 elems ----
        __shared__ int sdata[256];
        int b = blockIdx.x - NCONV;
        int t = threadIdx.x;
        const int* src = bounds + b * S_ + t * 16;
        int vals[16];
        int run = 0;
#pragma unroll
        for (int i = 0; i < 16; ++i) { run += src[i]; vals[i] = run; }
        sdata[t] = run;
        __syncthreads();
        for (int off = 1; off < 256; off <<= 1) {
            int v = (t >= off) ? sdata[t - off] : 0;
            __syncthreads();
            sdata[t] += v;
            __syncthreads();
        }
        int prefix = (t > 0) ? sdata[t - 1] : 0;
        int* dst = pidx + b * S_ + t * 16;
#pragma unroll
        for (int i = 0; i < 16; ++i) dst[i] = prefix + vals[i];
        return;
    }
    // ---- convert path ----
    const int NQ = (B_ * S_ * D_) / 4;      // 2097152
    const int NP = (B_ * P_ * D_) / 4;      // 524288
    const int NW = (D_ * D_) / 4;           // 262144
    int i = blockIdx.x * 256 + threadIdx.x;
    const float* src;
    unsigned short* dst;
    int j;
    if (i < NQ) { src = queries; dst = qb; j = i; }
    else if (i < NQ + NP) { src = patches; dst = pb; j = i - NQ; }
    else {
        int k = i - NQ - NP;
        int wsel = k >> 18;                  // NW = 2^18
        j = k & (NW - 1);
        if (wsel == 0) { src = wq; dst = wqb; }
        else if (wsel == 1) { src = wk; dst = wkb; }
        else if (wsel == 2) { src = wv; dst = wvb; }
        else { src = wo; dst = wob; }
    }
    float4 v = ((const float4*)src)[j];
    ushort4 o;
    o.x = f2bf(v.x); o.y = f2bf(v.y); o.z = f2bf(v.z); o.w = f2bf(v.w);
    ((ushort4*)dst)[j] = o;
}

// ---------------------------------------------------------------------------
// Fused QKV projection: 128x128 tile, global_load_lds staging, BK=32, 4 waves.
// blockIdx.z: 0 = Q-proj (M=8192, bf16 out * KSCALE)
//             1 = K-proj (M=2048, bf16 out)         [by < 16]
//             2 = V-proj (M=2048, bf16 transposed per-head, sigma-permuted
//                 within each 64-col tile of the patch dimension)
// ---------------------------------------------------------------------------
__global__ __launch_bounds__(256) void xattn_gemm_qkv(
    const unsigned short* __restrict__ qb, const unsigned short* __restrict__ pb,
    const unsigned short* __restrict__ wqb, const unsigned short* __restrict__ wkb,
    const unsigned short* __restrict__ wvb,
    const float* __restrict__ bq, const float* __restrict__ bk,
    const float* __restrict__ bv,
    unsigned short* __restrict__ Qout, unsigned short* __restrict__ Kout,
    unsigned short* __restrict__ Vout) {
    const int K = 1024, N = 1024;
    const int z = blockIdx.z;
    if (z > 0 && blockIdx.y >= 16) return;
    const unsigned short* A = (z == 0) ? qb : pb;
    const unsigned short* W = (z == 0) ? wqb : ((z == 1) ? wkb : wvb);
    const float* bias = (z == 0) ? bq : ((z == 1) ? bk : bv);

    __shared__ unsigned short As[128 * 32];
    __shared__ unsigned short Bs[128 * 32];

    const int m0 = blockIdx.y * 128;
    const int n0 = blockIdx.x * 128;
    const int t = threadIdx.x;
    const int w = t >> 6;
    const int l = t & 63;
    const int fr = l & 15, fq = l >> 4;
    const int wr = w >> 1, wc = w & 1;

    const int r0s = t >> 2;
    const int cs = (t & 3) * 8;
    const unsigned short* Ap0 = A + (size_t)(m0 + r0s) * K + cs;
    const unsigned short* Ap1 = A + (size_t)(m0 + 64 + r0s) * K + cs;
    const unsigned short* Wp0 = W + (size_t)(n0 + r0s) * K + cs;
    const unsigned short* Wp1 = W + (size_t)(n0 + 64 + r0s) * K + cs;
    const unsigned short* lA0 = &As[(w * 64) * 8];
    const unsigned short* lA1 = &As[(256 + w * 64) * 8];
    const unsigned short* lB0 = &Bs[(w * 64) * 8];
    const unsigned short* lB1 = &Bs[(256 + w * 64) * 8];

    f32x4 acc[4][4];
#pragma unroll
    for (int i = 0; i < 4; ++i)
#pragma unroll
        for (int j = 0; j < 4; ++j) acc[i][j] = (f32x4){0.f, 0.f, 0.f, 0.f};

    for (int k0 = 0; k0 < K; k0 += 32) {
        gll16(Ap0 + k0, lA0);
        gll16(Ap1 + k0, lA1);
        gll16(Wp0 + k0, lB0);
        gll16(Wp1 + k0, lB1);
        __syncthreads();
        short8 af[4], bf[4];
#pragma unroll
        for (int i = 0; i < 4; ++i)
            af[i] = *(const short8*)&As[(wr * 64 + i * 16 + fr) * 32 + fq * 8];
#pragma unroll
        for (int j = 0; j < 4; ++j)
            bf[j] = *(const short8*)&Bs[(wc * 64 + j * 16 + fr) * 32 + fq * 8];
#pragma unroll
        for (int i = 0; i < 4; ++i)
#pragma unroll
            for (int j = 0; j < 4; ++j)
                acc[i][j] = __builtin_amdgcn_mfma_f32_16x16x32_bf16(af[i], bf[j], acc[i][j], 0, 0, 0);
        __syncthreads();
    }

#pragma unroll
    for (int j = 0; j < 4; ++j) {
        int n = n0 + wc * 64 + j * 16 + fr;
        float bvv = bias[n];
#pragma unroll
        for (int i = 0; i < 4; ++i) {
            int mbase = m0 + wr * 64 + i * 16 + fq * 4;
#pragma unroll
            for (int r = 0; r < 4; ++r) {
                float val = acc[i][j][r] + bvv;
                int m = mbase + r;
                if (z == 0) {
                    Qout[(size_t)m * N + n] = f2bf(val * KSCALE);
                } else if (z == 1) {
                    Kout[(size_t)m * N + n] = f2bf(val);
                } else {
                    int bb = m >> 10, c = m & (P_ - 1);
                    int hh = n >> 6, d = n & 63;
                    int cl = c & 63;
                    int cp = (c & 960) | (((cl & 15) << 2) | (cl >> 4)); // sigma
                    Vout[(((size_t)(bb * H_ + hh)) * 64 + d) * P_ + cp] = f2bf(val);
                }
            }
        }
    }
}

// ---------------------------------------------------------------------------
// 128x128-tile GEMM, global_load_lds staging, fp32 out (O projection).
// ---------------------------------------------------------------------------
__global__ __launch_bounds__(256) void xattn_gemm_o(
    const unsigned short* __restrict__ A,
    const unsigned short* __restrict__ W,
    const float* __restrict__ bias,
    float* __restrict__ Cout) {
    const int K = 1024, N = 1024;
    __shared__ unsigned short As[128 * 32];
    __shared__ unsigned short Bs[128 * 32];

    const int m0 = blockIdx.y * 128;
    const int n0 = blockIdx.x * 128;
    const int t = threadIdx.x;
    const int w = t >> 6;
    const int l = t & 63;
    const int fr = l & 15, fq = l >> 4;
    const int wr = w >> 1, wc = w & 1;

    const int r0s = t >> 2;
    const int cs = (t & 3) * 8;
    const unsigned short* Ap0 = A + (size_t)(m0 + r0s) * K + cs;
    const unsigned short* Ap1 = A + (size_t)(m0 + 64 + r0s) * K + cs;
    const unsigned short* Wp0 = W + (size_t)(n0 + r0s) * K + cs;
    const unsigned short* Wp1 = W + (size_t)(n0 + 64 + r0s) * K + cs;
    const unsigned short* lA0 = &As[(w * 64) * 8];
    const unsigned short* lA1 = &As[(256 + w * 64) * 8];
    const unsigned short* lB0 = &Bs[(w * 64) * 8];
    const unsigned short* lB1 = &Bs[(256 + w * 64) * 8];

    f32x4 acc[4][4];
#pragma unroll
    for (int i = 0; i < 4; ++i)
#pragma unroll
        for (int j = 0; j < 4; ++j) acc[i][j] = (f32x4){0.f, 0.f, 0.f, 0.f};

    for (int k0 = 0; k0 < K; k0 += 32) {
        gll16(Ap0 + k0, lA0);
        gll16(Ap1 + k0, lA1);
        gll16(Wp0 + k0, lB0);
        gll16(Wp1 + k0, lB1);
        __syncthreads();
        short8 af[4], bf[4];
#pragma unroll
        for (int i = 0; i < 4; ++i)
            af[i] = *(const short8*)&As[(wr * 64 + i * 16 + fr) * 32 + fq * 8];
#pragma unroll
        for (int j = 0; j < 4; ++j)
            bf[j] = *(const short8*)&Bs[(wc * 64 + j * 16 + fr) * 32 + fq * 8];
#pragma unroll
        for (int i = 0; i < 4; ++i)
#pragma unroll
            for (int j = 0; j < 4; ++j)
                acc[i][j] = __builtin_amdgcn_mfma_f32_16x16x32_bf16(af[i], bf[j], acc[i][j], 0, 0, 0);
        __syncthreads();
    }

#pragma unroll
    for (int j = 0; j < 4; ++j) {
        int n = n0 + wc * 64 + j * 16 + fr;
        float bvv = bias[n];
#pragma unroll
        for (int i = 0; i < 4; ++i) {
            int mbase = m0 + wr * 64 + i * 16 + fq * 4;
#pragma unroll
            for (int r = 0; r < 4; ++r)
                Cout[(size_t)(mbase + r) * N + n] = acc[i][j][r] + bvv;
        }
    }
}

// ---------------------------------------------------------------------------
// MFMA flash attention (R3 staging + sigma-permuted PV + cheap softmax).
// Block = 4 waves, 64 q-rows. Per tile:
//   QK^T: 8 MFMA32 (Q regs, K LDS). raw v_exp_f32, boundary-only mask.
//   P pack: v_perm truncation, 4x ds_write_b64 into sigma-permuted columns.
//   PV: 8 MFMA32 (P LDS A-frags, V^T LDS B-frags; both sigma-permuted in k).
// ---------------------------------------------------------------------------
__global__ __launch_bounds__(256) void xattn_attn_mfma(
    const unsigned short* __restrict__ Qb,   // [B*S][D] bf16 (pre-scaled)
    const unsigned short* __restrict__ Kb,   // [B*P][D] bf16
    const unsigned short* __restrict__ Vtb,  // [B][H][64][P] bf16, sigma-perm
    const int* __restrict__ pidx,
    unsigned short* __restrict__ Ob) {       // [B*S][D] bf16
    __shared__ unsigned short Ks[64 * 72];
    __shared__ unsigned short Vs[64 * 72];
    __shared__ unsigned short Ps[64 * 72];

    const int q0 = (63 - blockIdx.x) * 64;   // LPT: heavy blocks dispatch first
    const int h = blockIdx.y;
    const int b = blockIdx.z;
    const int t = threadIdx.x;
    const int w = t >> 6, l = t & 63;
    const int fr = l & 15, fq = l >> 4;

    // Q A-frags, loaded once
    const unsigned short* qrow =
        Qb + (size_t)(b * S_ + q0 + w * 16 + fr) * D_ + h * DH_ + fq * 8;
    short8 qf0 = *(const short8*)qrow;
    short8 qf1 = *(const short8*)(qrow + 32);

    int prow[4];
#pragma unroll
    for (int r = 0; r < 4; ++r)
        prow[r] = pidx[b * S_ + q0 + w * 16 + fq * 4 + r];
    const int limit = pidx[b * S_ + q0 + 63];       // monotone in s
    const int ntiles = (min(limit, P_ - 1) + 64) >> 6;
    const int nfull = (pidx[b * S_ + q0] + 1) >> 6; // tiles needing no mask

    float lsum[4] = {0.f, 0.f, 0.f, 0.f};
    f32x4 oacc[4];
#pragma unroll
    for (int nt = 0; nt < 4; ++nt) oacc[nt] = (f32x4){0.f, 0.f, 0.f, 0.f};

    const int srow = t >> 3, sseg = t & 7;
    const unsigned short* kbase = Kb + (size_t)(b * P_) * D_ + h * DH_;
    const unsigned short* vbase = Vtb + (size_t)(b * H_ + h) * 64 * P_;

    for (int kt = 0; kt < ntiles; ++kt) {
        const int c0 = kt * 64;
        __syncthreads();   // protect LDS from previous tile's readers
        *(uint4*)&Ks[srow * 72 + sseg * 8] =
            *(const uint4*)(kbase + (size_t)(c0 + srow) * D_ + sseg * 8);
        *(uint4*)&Ks[(srow + 32) * 72 + sseg * 8] =
            *(const uint4*)(kbase + (size_t)(c0 + srow + 32) * D_ + sseg * 8);
        *(uint4*)&Vs[srow * 72 + sseg * 8] =
            *(const uint4*)(vbase + (size_t)srow * P_ + c0 + sseg * 8);
        *(uint4*)&Vs[(srow + 32) * 72 + sseg * 8] =
            *(const uint4*)(vbase + (size_t)(srow + 32) * P_ + c0 + sseg * 8);
        __syncthreads();

        const int maskme = (kt >= nfull);
        // QK^T -> s[nt] (rows = w*16+fq*4+r, cols = nt*16+fr)
        f32x4 s[4];
#pragma unroll
        for (int nt = 0; nt < 4; ++nt) {
            short8 kf0 = *(const short8*)&Ks[(nt * 16 + fr) * 72 + fq * 8];
            short8 kf1 = *(const short8*)&Ks[(nt * 16 + fr) * 72 + 32 + fq * 8];
            f32x4 a = (f32x4){0.f, 0.f, 0.f, 0.f};
            a = __builtin_amdgcn_mfma_f32_16x16x32_bf16(qf0, kf0, a, 0, 0, 0);
            a = __builtin_amdgcn_mfma_f32_16x16x32_bf16(qf1, kf1, a, 0, 0, 0);
            s[nt] = a;
        }
        // exp2 (raw) + boundary mask + lsum
        if (maskme) {
#pragma unroll
            for (int nt = 0; nt < 4; ++nt) {
                const int col = c0 + nt * 16 + fr;
#pragma unroll
                for (int r = 0; r < 4; ++r) {
                    float p = EXP2(s[nt][r]);
                    p = (col > prow[r]) ? 0.f : p;
                    s[nt][r] = p;
                    lsum[r] += p;
                }
            }
        } else {
#pragma unroll
            for (int nt = 0; nt < 4; ++nt) {
#pragma unroll
                for (int r = 0; r < 4; ++r) {
                    float p = EXP2(s[nt][r]);
                    s[nt][r] = p;
                    lsum[r] += p;
                }
            }
        }
        // pack P row-wise into sigma-permuted columns: position fr*4+nt
        // holds col c = nt*16+fr  (perm truncation: p -> bf16)
#pragma unroll
        for (int r = 0; r < 4; ++r) {
            uint2 pk;
            pk.x = __builtin_amdgcn_perm(__float_as_uint(s[1][r]),
                                         __float_as_uint(s[0][r]), 0x07060302u);
            pk.y = __builtin_amdgcn_perm(__float_as_uint(s[3][r]),
                                         __float_as_uint(s[2][r]), 0x07060302u);
            *(uint2*)&Ps[(w * 16 + fq * 4 + r) * 72 + fr * 4] = pk;
        }
        // PV (A = P rows, B = V^T rows; k sigma-permuted on both sides)
        short8 pf0 = *(const short8*)&Ps[(w * 16 + fr) * 72 + fq * 8];
        short8 pf1 = *(const short8*)&Ps[(w * 16 + fr) * 72 + 32 + fq * 8];
#pragma unroll
        for (int nt = 0; nt < 4; ++nt) {
            short8 vf0 = *(const short8*)&Vs[(nt * 16 + fr) * 72 + fq * 8];
            short8 vf1 = *(const short8*)&Vs[(nt * 16 + fr) * 72 + 32 + fq * 8];
            oacc[nt] = __builtin_amdgcn_mfma_f32_16x16x32_bf16(pf0, vf0, oacc[nt], 0, 0, 0);
            oacc[nt] = __builtin_amdgcn_mfma_f32_16x16x32_bf16(pf1, vf1, oacc[nt], 0, 0, 0);
        }
    }

    // l reduction across the 16 fr lanes of each quad-group
#pragma unroll
    for (int off = 1; off < 16; off <<= 1) {
#pragma unroll
        for (int r = 0; r < 4; ++r)
            lsum[r] += __shfl_xor(lsum[r], off);
    }
    float inv[4];
#pragma unroll
    for (int r = 0; r < 4; ++r) inv[r] = 1.0f / lsum[r];

    unsigned short* obase = Ob + (size_t)(b * S_ + q0 + w * 16) * D_ + h * DH_;
#pragma unroll
    for (int nt = 0; nt < 4; ++nt)
#pragma unroll
        for (int r = 0; r < 4; ++r)
            obase[(size_t)(fq * 4 + r) * D_ + nt * 16 + fr] =
                f2bf(oacc[nt][r] * inv[r]);
}

// ---------------------------------------------------------------------------
// launch
// ---------------------------------------------------------------------------
extern "C" void kernel_launch(void* const* d_in, const int* in_sizes, int n_in,
                              void* d_out, int out_size, void* d_ws, size_t ws_size,
                              hipStream_t stream) {
    const float* queries = (const float*)d_in[0];
    const float* patches = (const float*)d_in[1];
    const int* bounds    = (const int*)d_in[2];
    const float* wq = (const float*)d_in[3];
    const float* wk = (const float*)d_in[4];
    const float* wv = (const float*)d_in[5];
    const float* wo = (const float*)d_in[6];
    const float* bq = (const float*)d_in[7];
    const float* bk = (const float*)d_in[8];
    const float* bv = (const float*)d_in[9];
    const float* bo = (const float*)d_in[10];
    float* out = (float*)d_out;

    char* ws = (char*)d_ws;
    unsigned short* qb    = (unsigned short*)(ws + 0);          // 16777216
    unsigned short* pb    = (unsigned short*)(ws + 16777216);   // 4194304
    unsigned short* wqb   = (unsigned short*)(ws + 20971520);   // 2097152
    unsigned short* wkb   = (unsigned short*)(ws + 23068672);
    unsigned short* wvb   = (unsigned short*)(ws + 25165824);
    unsigned short* wob   = (unsigned short*)(ws + 27262976);
    unsigned short* Qbf   = (unsigned short*)(ws + 29360128);   // 16777216
    unsigned short* Kbf   = (unsigned short*)(ws + 46137344);   // 4194304
    unsigned short* Vtb   = (unsigned short*)(ws + 50331648);   // 4194304
    unsigned short* attnb = (unsigned short*)(ws + 54525952);   // 16777216
    int* pidx             = (int*)(ws + 71303168);              // 32768

    // 1. fused converts + cumsum
    xattn_convert_all<<<dim3(NCONV + B_), 256, 0, stream>>>(
        queries, patches, wq, wk, wv, wo, qb, pb, wqb, wkb, wvb, wob,
        bounds, pidx);
    // 2. fused Q/K/V projections (one launch; V sigma-permuted per 64-tile)
    xattn_gemm_qkv<<<dim3(8, 64, 3), 256, 0, stream>>>(
        qb, pb, wqb, wkb, wvb, bq, bk, bv, Qbf, Kbf, Vtb);
    // 3. MFMA flash attention
    xattn_attn_mfma<<<dim3(S_ / 64, H_, B_), 256, 0, stream>>>(
        Qbf, Kbf, Vtb, pidx, attnb);
    // 4. output projection (fp32 out)
    xattn_gemm_o<<<dim3(8, 64), 256, 0, stream>>>(attnb, wob, bo, out);
}